// Round 11
// baseline (250.752 us; speedup 1.0000x reference)
//
#include <hip/hip_runtime.h>

typedef float f32x4 __attribute__((ext_vector_type(4)));
typedef _Float16 f16x4 __attribute__((ext_vector_type(4)));
typedef unsigned int u32x4 __attribute__((ext_vector_type(4)));
typedef __bf16 bf16x8_t __attribute__((ext_vector_type(8)));
typedef __bf16 bf16x4_t __attribute__((ext_vector_type(4)));

#define DEVFN static __device__ __forceinline__

constexpr int BHN = 16;    // B*H
constexpr int SN  = 2048;
constexpr int DN  = 64;
constexpr size_t CTXN = (size_t)BHN * SN * DN;   // 2,097,152
constexpr int NK = 4;     // k-split chunks (both passes) — R8-proven
// K pre-scale: (1/sqrt(64)) * log2(e) so QK^T accumulates s*log2e -> v_exp direct
constexpr float KSCL = 0.18033688f;

// ---- MFMA asm with internal hazard fencing (verified R2-R10).
DEVFN void qk4_mfma(f32x4& dA, f32x4& dB, bf16x8_t k0v, bf16x8_t k1v,
                    bf16x8_t qA0, bf16x8_t qA1, bf16x8_t qB0, bf16x8_t qB1) {
  asm volatile("s_nop 3\n\t"
               "v_mfma_f32_16x16x32_bf16 %0, %2, %4, %0\n\t"
               "v_mfma_f32_16x16x32_bf16 %1, %2, %6, %1\n\t"
               "v_mfma_f32_16x16x32_bf16 %0, %3, %5, %0\n\t"
               "v_mfma_f32_16x16x32_bf16 %1, %3, %7, %1\n\t"
               "s_nop 7\n\ts_nop 7"
               : "+v"(dA), "+v"(dB)
               : "v"(k0v), "v"(k1v), "v"(qA0), "v"(qA1), "v"(qB0), "v"(qB1));
}

DEVFN void pv8_mfma(f32x4& a0, f32x4& a1, f32x4& a2, f32x4& a3,
                    f32x4& b0, f32x4& b1, f32x4& b2, f32x4& b3,
                    bf16x4_t paA, bf16x4_t paB,
                    bf16x4_t v0, bf16x4_t v1, bf16x4_t v2, bf16x4_t v3) {
  asm volatile("s_nop 3\n\t"
               "v_mfma_f32_16x16x16_bf16 %0, %8, %10, %0\n\t"
               "v_mfma_f32_16x16x16_bf16 %4, %9, %10, %4\n\t"
               "v_mfma_f32_16x16x16_bf16 %1, %8, %11, %1\n\t"
               "v_mfma_f32_16x16x16_bf16 %5, %9, %11, %5\n\t"
               "v_mfma_f32_16x16x16_bf16 %2, %8, %12, %2\n\t"
               "v_mfma_f32_16x16x16_bf16 %6, %9, %12, %6\n\t"
               "v_mfma_f32_16x16x16_bf16 %3, %8, %13, %3\n\t"
               "v_mfma_f32_16x16x16_bf16 %7, %9, %13, %7\n\t"
               "s_nop 7\n\ts_nop 7"
               : "+v"(a0), "+v"(a1), "+v"(a2), "+v"(a3),
                 "+v"(b0), "+v"(b1), "+v"(b2), "+v"(b3)
               : "v"(paA), "v"(paB), "v"(v0), "v"(v1), "v"(v2), "v"(v3));
}

// 4 independent v_exp_f32 (2^x), trailing s_nop 1 covers TRANS->VALU hazard.
DEVFN void exp2x4(float& a, float& b, float& c, float& d) {
  asm volatile("v_exp_f32 %0, %0\n\t"
               "v_exp_f32 %1, %1\n\t"
               "v_exp_f32 %2, %2\n\t"
               "v_exp_f32 %3, %3\n\t"
               "s_nop 1"
               : "+v"(a), "+v"(b), "+v"(c), "+v"(d));
}

// ---- FUSED prep: [0,2048) pack mask->bmT; [2048,3072) Q->bf16;
// [3072,4096) K->bf16*KSCL; [4096,4352) V->tiled Vt.
constexpr int PB = 2048, QB = 1024, KB = 1024, VB = 256;

__global__ __launch_bounds__(256) void prep_kernel(
    const void* __restrict__ mraw, unsigned int* __restrict__ bmT,
    const float* __restrict__ Q, const float* __restrict__ K,
    const float* __restrict__ V, __bf16* __restrict__ Qb,
    __bf16* __restrict__ Kb, __bf16* __restrict__ Vt) {
  const int bid = blockIdx.x;
  const int tidl = threadIdx.x;
  if (bid < PB) {
    __shared__ unsigned int sfl;
    if (tidl == 0) sfl = 0;
    __syncthreads();
    {
      unsigned int f = 0;
      const unsigned int* m32 = (const unsigned int*)mraw;
      for (int i = tidl; i < 4096; i += 256) {
        unsigned int w = m32[i];
        if (w == 0x3F800000u) f |= 2u;
        else if (w > 1u) f |= 1u;
      }
      if (f) atomicOr(&sfl, f);
    }
    __syncthreads();
    const unsigned int fl = (sfl & 2u) ? 2u : ((sfl & 1u) ? 1u : 0u);
    const int tid = bid * 256 + tidl;
    const int NT  = PB * 256;
    if (fl != 1u) {
      const int W = BHN * (SN / 32) * SN;          // 2,097,152
      const unsigned int* m32 = (const unsigned int*)mraw;
      for (int w = tid; w < W; w += NT) {
        const int q   = w & (SN - 1);
        const int kc2 = (w >> 11) & (SN / 32 - 1);
        const int bh  = w >> 17;
        const unsigned int* src = m32 + ((size_t)(bh * SN + q) * SN) + kc2 * 32;
        unsigned int r = 0;
        #pragma unroll
        for (int j = 0; j < 8; ++j) {
          u32x4 v = *(const u32x4*)(src + j * 4);
          r |= ((unsigned)(v[0] != 0u)) << (4 * j)
             | ((unsigned)(v[1] != 0u)) << (4 * j + 1)
             | ((unsigned)(v[2] != 0u)) << (4 * j + 2)
             | ((unsigned)(v[3] != 0u)) << (4 * j + 3);
        }
        bmT[w] = r;
      }
    } else {
      const int W4 = BHN * (SN / 128) * SN;        // 524,288
      const unsigned char* m8 = (const unsigned char*)mraw;
      for (int w4 = tid; w4 < W4; w4 += NT) {
        const int q   = w4 & (SN - 1);
        const int kc8 = (w4 >> 11) & (SN / 128 - 1);
        const int bh  = w4 >> 15;
        const unsigned char* src = m8 + ((size_t)(bh * SN + q) * SN) + kc8 * 128;
        #pragma unroll
        for (int i = 0; i < 4; ++i) {
          const unsigned int* s32 = (const unsigned int*)(src + 32 * i);
          unsigned int r = 0;
          #pragma unroll
          for (int j = 0; j < 8; ++j) {
            unsigned int x = s32[j];
            r |= ((unsigned)((x & 0x000000FFu) != 0u)) << (4 * j)
               | ((unsigned)((x & 0x0000FF00u) != 0u)) << (4 * j + 1)
               | ((unsigned)((x & 0x00FF0000u) != 0u)) << (4 * j + 2)
               | ((unsigned)((x & 0xFF000000u) != 0u)) << (4 * j + 3);
          }
          bmT[((size_t)(bh * (SN / 32) + kc8 * 4 + i)) * SN + q] = r;
        }
      }
    }
  } else if (bid < PB + QB + KB) {
    const bool isK = (bid >= PB + QB);
    const int rb = bid - (isK ? PB + QB : PB);
    const float* src = isK ? K : Q;
    __bf16* dst = isK ? Kb : Qb;
    const float scale = isK ? KSCL : 1.0f;
    const size_t i = ((size_t)rb * 256 + tidl) * 8;
    f32x4 v0 = *(const f32x4*)(src + i);
    f32x4 v1 = *(const f32x4*)(src + i + 4);
    bf16x8_t o;
    o[0]=(__bf16)(v0[0]*scale); o[1]=(__bf16)(v0[1]*scale);
    o[2]=(__bf16)(v0[2]*scale); o[3]=(__bf16)(v0[3]*scale);
    o[4]=(__bf16)(v1[0]*scale); o[5]=(__bf16)(v1[1]*scale);
    o[6]=(__bf16)(v1[2]*scale); o[7]=(__bf16)(v1[3]*scale);
    *(bf16x8_t*)(dst + i) = o;
  } else {
    const int vb = bid - (PB + QB + KB);
    const int lane = tidl & 63, wv = tidl >> 6;
    const int k0 = ((vb & 15) * 4 + wv) * 32;
    const int bh = vb >> 4;
    const float* src = V + (size_t)bh * SN * DN;
    __bf16* dst = Vt + (((size_t)bh * (SN / 32) + (k0 >> 5)) * DN + lane) * 32;
    bf16x8_t w0, w1, w2, w3;
    #pragma unroll
    for (int i = 0; i < 8; ++i) {
      w0[i] = (__bf16)src[(size_t)(k0 + i) * DN + lane];
      w1[i] = (__bf16)src[(size_t)(k0 + 8 + i) * DN + lane];
      w2[i] = (__bf16)src[(size_t)(k0 + 16 + i) * DN + lane];
      w3[i] = (__bf16)src[(size_t)(k0 + 24 + i) * DN + lane];
    }
    *(bf16x8_t*)(dst)      = w0;
    *(bf16x8_t*)(dst + 8)  = w1;
    *(bf16x8_t*)(dst + 16) = w2;
    *(bf16x8_t*)(dst + 24) = w3;
  }
}

// XCD-pinning decode (1024 blocks): bid&7 == bh&7.
DEVFN void swz_decode(int bid, int& bh, int& c, int& x) {
  const int xcd = bid & 7, s8 = bid >> 3;   // s8: 0..127
  bh = xcd + 8 * (s8 >> 6);
  const int r6 = s8 & 63;
  c = r6 >> 4;
  x = r6 & 15;
}

// ---- pass 1: l-partials (l = sum 2^acc). LDS-staged K 64-k tiles (R8 body,
// exp2 instead of mul+exp).
__global__ __launch_bounds__(256, 4) void attn_l_kernel(
    const __bf16* __restrict__ Qb, const __bf16* __restrict__ Kb,
    const unsigned int* __restrict__ bmT, float* __restrict__ lpart) {
  __shared__ __align__(16) char Ks[2][8192];
  const int tid = threadIdx.x;
  const int lane = tid & 63, wv = tid >> 6;
  const int qr = lane & 15, g = lane >> 4;
  int bh, c, x;
  swz_decode(blockIdx.x, bh, c, x);
  const int q0 = x * 128 + wv * 32;
  const int CS = SN / NK, kbase = c * CS;    // 512
  const int NT = CS / 64;                    // 8 tiles

  const __bf16* Qbb = Qb + (size_t)bh * SN * DN;
  const int qA = q0 + qr, qB = q0 + 16 + qr;
  bf16x8_t qfA0 = *(const bf16x8_t*)(Qbb + (size_t)qA * DN + 8 * g);
  bf16x8_t qfA1 = *(const bf16x8_t*)(Qbb + (size_t)qA * DN + 32 + 8 * g);
  bf16x8_t qfB0 = *(const bf16x8_t*)(Qbb + (size_t)qB * DN + 8 * g);
  bf16x8_t qfB1 = *(const bf16x8_t*)(Qbb + (size_t)qB * DN + 32 + 8 * g);
  const size_t rowA = (size_t)bh * SN + qA;
  const size_t rowB = (size_t)bh * SN + qB;
  const unsigned int* bmb = bmT + (size_t)bh * (SN / 32) * SN;
  const int kb2 = kbase >> 5;

  const int krow = tid >> 2;                 // 0..63
  const int kcol = (tid & 3) * 32;
  const int swz  = (krow & 7) << 4;
  const int kdst0 = krow * 128 + ((kcol     ) ^ swz);
  const int kdst1 = krow * 128 + ((kcol + 16) ^ swz);
  const char* Ksrc = (const char*)(Kb + (size_t)bh * SN * DN + (size_t)kbase * DN);

  {
    u32x4 a = *(const u32x4*)(Ksrc + krow * 128 + kcol);
    u32x4 b = *(const u32x4*)(Ksrc + krow * 128 + kcol + 16);
    *(u32x4*)&Ks[0][kdst0] = a;
    *(u32x4*)&Ks[0][kdst1] = b;
  }
  __syncthreads();

  float lA = 0.f, lB = 0.f;
  for (int tt = 0; tt < NT; ++tt) {
    const bool pf = (tt + 1 < NT);
    u32x4 a, b;
    if (pf) {
      a = *(const u32x4*)(Ksrc + (tt + 1) * 8192 + krow * 128 + kcol);
      b = *(const u32x4*)(Ksrc + (tt + 1) * 8192 + krow * 128 + kcol + 16);
    }
    const char* Kbuf = Ks[tt & 1];
    const unsigned int wA0 = bmb[(size_t)(kb2 + 2 * tt    ) * SN + qA];
    const unsigned int wA1 = bmb[(size_t)(kb2 + 2 * tt + 1) * SN + qA];
    const unsigned int wB0 = bmb[(size_t)(kb2 + 2 * tt    ) * SN + qB];
    const unsigned int wB1 = bmb[(size_t)(kb2 + 2 * tt + 1) * SN + qB];
    #pragma unroll
    for (int s = 0; s < 4; ++s) {
      const int rk = 16 * s + qr;
      const int rsw = (rk & 7) << 4;
      bf16x8_t kf0 = *(const bf16x8_t*)&Kbuf[rk * 128 + ((16 * g     ) ^ rsw)];
      bf16x8_t kf1 = *(const bf16x8_t*)&Kbuf[rk * 128 + ((64 + 16 * g) ^ rsw)];
      f32x4 aA = {0,0,0,0}, aB = {0,0,0,0};
      qk4_mfma(aA, aB, kf0, kf1, qfA0, qfA1, qfB0, qfB1);
      const unsigned int wmA = (s < 2) ? wA0 : wA1;
      const unsigned int wmB = (s < 2) ? wB0 : wB1;
      const int sh = (s & 1) * 16 + 4 * g;
      float eA0 = aA[0], eA1 = aA[1], eA2 = aA[2], eA3 = aA[3];
      float eB0 = aB[0], eB1 = aB[1], eB2 = aB[2], eB3 = aB[3];
      exp2x4(eA0, eA1, eA2, eA3);
      exp2x4(eB0, eB1, eB2, eB3);
      lA += ((wmA >> (sh + 0)) & 1u) ? 0.f : eA0;
      lA += ((wmA >> (sh + 1)) & 1u) ? 0.f : eA1;
      lA += ((wmA >> (sh + 2)) & 1u) ? 0.f : eA2;
      lA += ((wmA >> (sh + 3)) & 1u) ? 0.f : eA3;
      lB += ((wmB >> (sh + 0)) & 1u) ? 0.f : eB0;
      lB += ((wmB >> (sh + 1)) & 1u) ? 0.f : eB1;
      lB += ((wmB >> (sh + 2)) & 1u) ? 0.f : eB2;
      lB += ((wmB >> (sh + 3)) & 1u) ? 0.f : eB3;
    }
    if (pf) {
      char* Kn = Ks[(tt + 1) & 1];
      *(u32x4*)&Kn[kdst0] = a;
      *(u32x4*)&Kn[kdst1] = b;
    }
    __syncthreads();
  }
  lA = lA + __shfl_xor(lA, 16); lA = lA + __shfl_xor(lA, 32);
  lB = lB + __shfl_xor(lB, 16); lB = lB + __shfl_xor(lB, 32);
  if (g == 0) {
    lpart[rowA * NK + c] = lA;
    lpart[rowB * NK + c] = lB;
  }
}

// ---- pass 2: 64-k tiles (8 barriers), normalizer folded into MFMA C-input:
// acc = S*log2e + log2(1/l); p = 2^acc; masked -> 0. Plain attn stores.
__global__ __launch_bounds__(256, 4) void attn_out_kernel(
    const __bf16* __restrict__ Qb, const __bf16* __restrict__ Kb,
    const __bf16* __restrict__ Vt, const unsigned int* __restrict__ bmT,
    const float* __restrict__ lpart, _Float16* __restrict__ cp,
    float* __restrict__ attn) {
  __shared__ __align__(16) char Ks[2][8192];
  __shared__ __align__(16) char Vs[2][8192];
  const int tid = threadIdx.x;
  const int lane = tid & 63, wv = tid >> 6;
  const int qr = lane & 15, g = lane >> 4;
  int bh, c, x;
  swz_decode(blockIdx.x, bh, c, x);
  const int q0 = x * 128 + wv * 32;
  const int CS = SN / NK, kbase = c * CS;   // 512
  const int NT = CS / 64;                   // 8 tiles

  const __bf16* Qbb = Qb + (size_t)bh * SN * DN;
  const int qA = q0 + qr, qB = q0 + 16 + qr;
  bf16x8_t qfA0 = *(const bf16x8_t*)(Qbb + (size_t)qA * DN + 8 * g);
  bf16x8_t qfA1 = *(const bf16x8_t*)(Qbb + (size_t)qA * DN + 32 + 8 * g);
  bf16x8_t qfB0 = *(const bf16x8_t*)(Qbb + (size_t)qB * DN + 8 * g);
  bf16x8_t qfB1 = *(const bf16x8_t*)(Qbb + (size_t)qB * DN + 32 + 8 * g);
  const size_t rowA = (size_t)bh * SN + qA;
  const size_t rowB = (size_t)bh * SN + qB;
  f32x4 l4A = *(const f32x4*)(lpart + rowA * NK);
  f32x4 l4B = *(const f32x4*)(lpart + rowB * NK);
  const float lg2A = -__log2f(l4A[0] + l4A[1] + l4A[2] + l4A[3]);
  const float lg2B = -__log2f(l4B[0] + l4B[1] + l4B[2] + l4B[3]);
  const unsigned int* bmb = bmT + (size_t)bh * (SN / 32) * SN;
  float* arowA = attn + rowA * SN;
  float* arowB = attn + rowB * SN;
  const int kb2 = kbase >> 5;

  // K staging (64 rows x 128 B, dbuf, proven attn_l scheme)
  const int krow = tid >> 2;                 // 0..63
  const int kcol = (tid & 3) * 32;
  const int kswz = (krow & 7) << 4;
  const int kdst0 = krow * 128 + ((kcol     ) ^ kswz);
  const int kdst1 = krow * 128 + ((kcol + 16) ^ kswz);
  const char* Ksrc = (const char*)(Kb + (size_t)bh * SN * DN + (size_t)kbase * DN);
  // V staging: rows d (0..63) x 128 B (64 k x bf16); src = two 4 KB Vt tiles
  const int vd = tid >> 2;                   // 0..63
  const int vkb = (tid & 3) * 16;            // 0..48
  const int vswz = (vd & 15) << 3;
  const int vbase = vd * 128;
  const char* Vsrc = (const char*)Vt + ((size_t)bh * (SN / 32) + (kbase >> 5)) * 4096;

  f32x4 cA0 = {0,0,0,0}, cA1 = {0,0,0,0}, cA2 = {0,0,0,0}, cA3 = {0,0,0,0};
  f32x4 cB0 = {0,0,0,0}, cB1 = {0,0,0,0}, cB2 = {0,0,0,0}, cB3 = {0,0,0,0};

  // stage tile 0
  {
    u32x4 ka = *(const u32x4*)(Ksrc + krow * 128 + kcol);
    u32x4 kb = *(const u32x4*)(Ksrc + krow * 128 + kcol + 16);
    u32x4 va = *(const u32x4*)(Vsrc + vd * 64 + vkb);          // k 0..31 half
    u32x4 vb = *(const u32x4*)(Vsrc + 4096 + vd * 64 + vkb);   // k 32..63 half
    *(u32x4*)&Ks[0][kdst0] = ka;
    *(u32x4*)&Ks[0][kdst1] = kb;
    *(unsigned long long*)&Vs[0][vbase + ((vkb     ) ^ vswz)] = ((unsigned long long)va[1] << 32) | va[0];
    *(unsigned long long*)&Vs[0][vbase + ((vkb +  8) ^ vswz)] = ((unsigned long long)va[3] << 32) | va[2];
    *(unsigned long long*)&Vs[0][vbase + ((64 + vkb    ) ^ vswz)] = ((unsigned long long)vb[1] << 32) | vb[0];
    *(unsigned long long*)&Vs[0][vbase + ((64 + vkb + 8) ^ vswz)] = ((unsigned long long)vb[3] << 32) | vb[2];
  }
  __syncthreads();

  for (int tt = 0; tt < NT; ++tt) {
    const bool pf = (tt + 1 < NT);
    u32x4 ka, kb, va, vb;
    if (pf) {   // T14: issue next-tile loads before compute
      ka = *(const u32x4*)(Ksrc + (tt + 1) * 8192 + krow * 128 + kcol);
      kb = *(const u32x4*)(Ksrc + (tt + 1) * 8192 + krow * 128 + kcol + 16);
      va = *(const u32x4*)(Vsrc + (tt + 1) * 8192 + vd * 64 + vkb);
      vb = *(const u32x4*)(Vsrc + (tt + 1) * 8192 + 4096 + vd * 64 + vkb);
    }
    const char* Kbuf = Ks[tt & 1];
    const char* Vbuf = Vs[tt & 1];
    const int ktg = kbase + tt * 64;
    const unsigned int wA0 = bmb[(size_t)(kb2 + 2 * tt    ) * SN + qA];
    const unsigned int wA1 = bmb[(size_t)(kb2 + 2 * tt + 1) * SN + qA];
    const unsigned int wB0 = bmb[(size_t)(kb2 + 2 * tt    ) * SN + qB];
    const unsigned int wB1 = bmb[(size_t)(kb2 + 2 * tt + 1) * SN + qB];
    #pragma unroll
    for (int s = 0; s < 4; ++s) {
      const int rk = 16 * s + qr;
      const int rsw = (rk & 7) << 4;
      bf16x8_t kf0 = *(const bf16x8_t*)&Kbuf[rk * 128 + ((16 * g     ) ^ rsw)];
      bf16x8_t kf1 = *(const bf16x8_t*)&Kbuf[rk * 128 + ((64 + 16 * g) ^ rsw)];
      const int vxor = (32 * s + 8 * g) ^ (qr << 3);   // (row&15)==qr for all 4 j
      bf16x4_t vf0 = *(const bf16x4_t*)&Vbuf[(qr     ) * 128 + vxor];
      bf16x4_t vf1 = *(const bf16x4_t*)&Vbuf[(qr + 16) * 128 + vxor];
      bf16x4_t vf2 = *(const bf16x4_t*)&Vbuf[(qr + 32) * 128 + vxor];
      bf16x4_t vf3 = *(const bf16x4_t*)&Vbuf[(qr + 48) * 128 + vxor];
      f32x4 aA = {lg2A, lg2A, lg2A, lg2A};
      f32x4 aB = {lg2B, lg2B, lg2B, lg2B};
      qk4_mfma(aA, aB, kf0, kf1, qfA0, qfA1, qfB0, qfB1);
      const unsigned int wmA = (s < 2) ? wA0 : wA1;
      const unsigned int wmB = (s < 2) ? wB0 : wB1;
      const int sh = (s & 1) * 16 + 4 * g;
      float pA0 = aA[0], pA1 = aA[1], pA2 = aA[2], pA3 = aA[3];
      float pB0 = aB[0], pB1 = aB[1], pB2 = aB[2], pB3 = aB[3];
      exp2x4(pA0, pA1, pA2, pA3);
      exp2x4(pB0, pB1, pB2, pB3);
      pA0 = ((wmA >> (sh + 0)) & 1u) ? 0.f : pA0;
      pA1 = ((wmA >> (sh + 1)) & 1u) ? 0.f : pA1;
      pA2 = ((wmA >> (sh + 2)) & 1u) ? 0.f : pA2;
      pA3 = ((wmA >> (sh + 3)) & 1u) ? 0.f : pA3;
      pB0 = ((wmB >> (sh + 0)) & 1u) ? 0.f : pB0;
      pB1 = ((wmB >> (sh + 1)) & 1u) ? 0.f : pB1;
      pB2 = ((wmB >> (sh + 2)) & 1u) ? 0.f : pB2;
      pB3 = ((wmB >> (sh + 3)) & 1u) ? 0.f : pB3;
      *(f32x4*)(arowA + ktg + 16 * s + 4 * g) = (f32x4){pA0, pA1, pA2, pA3};
      *(f32x4*)(arowB + ktg + 16 * s + 4 * g) = (f32x4){pB0, pB1, pB2, pB3};
      bf16x4_t paA = {(__bf16)pA0, (__bf16)pA1, (__bf16)pA2, (__bf16)pA3};
      bf16x4_t paB = {(__bf16)pB0, (__bf16)pB1, (__bf16)pB2, (__bf16)pB3};
      pv8_mfma(cA0, cA1, cA2, cA3, cB0, cB1, cB2, cB3, paA, paB, vf0, vf1, vf2, vf3);
    }
    if (pf) {   // write-late
      char* Kn = Ks[(tt + 1) & 1];
      char* Vn = Vs[(tt + 1) & 1];
      *(u32x4*)&Kn[kdst0] = ka;
      *(u32x4*)&Kn[kdst1] = kb;
      *(unsigned long long*)&Vn[vbase + ((vkb     ) ^ vswz)] = ((unsigned long long)va[1] << 32) | va[0];
      *(unsigned long long*)&Vn[vbase + ((vkb +  8) ^ vswz)] = ((unsigned long long)va[3] << 32) | va[2];
      *(unsigned long long*)&Vn[vbase + ((64 + vkb    ) ^ vswz)] = ((unsigned long long)vb[1] << 32) | vb[0];
      *(unsigned long long*)&Vn[vbase + ((64 + vkb + 8) ^ vswz)] = ((unsigned long long)vb[3] << 32) | vb[2];
    }
    __syncthreads();
  }
  _Float16* cdst = cp + (size_t)c * CTXN;
  const size_t baseo = (size_t)bh * SN * DN;
  #pragma unroll
  for (int j = 0; j < 4; ++j) {
    const size_t rA = baseo + (size_t)(q0 + 4 * g + j) * DN + qr;
    const size_t rB = baseo + (size_t)(q0 + 16 + 4 * g + j) * DN + qr;
    cdst[rA]      = (_Float16)cA0[j];
    cdst[rA + 16] = (_Float16)cA1[j];
    cdst[rA + 32] = (_Float16)cA2[j];
    cdst[rA + 48] = (_Float16)cA3[j];
    cdst[rB]      = (_Float16)cB0[j];
    cdst[rB + 16] = (_Float16)cB1[j];
    cdst[rB + 32] = (_Float16)cB2[j];
    cdst[rB + 48] = (_Float16)cB3[j];
  }
}

// ---- sum the NK f16 partial contexts -> f32 ctx.
__global__ __launch_bounds__(256) void ctx_reduce_kernel(
    const _Float16* __restrict__ cp, float* __restrict__ ctx) {
  const size_t i = ((size_t)blockIdx.x * 256 + threadIdx.x) * 4;
  f16x4 a = *(const f16x4*)(cp + i);
  f16x4 b = *(const f16x4*)(cp + CTXN + i);
  f16x4 d = *(const f16x4*)(cp + 2 * CTXN + i);
  f16x4 e = *(const f16x4*)(cp + 3 * CTXN + i);
  f32x4 s;
  #pragma unroll
  for (int k = 0; k < 4; ++k)
    s[k] = ((float)a[k] + (float)b[k]) + ((float)d[k] + (float)e[k]);
  __builtin_nontemporal_store(s, (f32x4*)(ctx + i));
}

extern "C" void kernel_launch(void* const* d_in, const int* in_sizes, int n_in,
                              void* d_out, int out_size, void* d_ws, size_t ws_size,
                              hipStream_t stream) {
  const float* Q = (const float*)d_in[0];
  const float* K = (const float*)d_in[1];
  const float* V = (const float*)d_in[2];
  const void*  mraw = d_in[3];

  float* out  = (float*)d_out;
  float* ctx  = out;                 // CTXN f32
  float* attn = out + CTXN;          // 67,108,864 f32

  // ws layout (~38 MB)
  char* wsb = (char*)d_ws;
  unsigned int* bmT = (unsigned int*)(wsb + 256);                 // 8 MB
  float* lp   = (float*)(wsb + 256 + 8388608);                    // 512 KB
  __bf16* Qb  = (__bf16*)(wsb + 256 + 8388608 + 524288);          // 4 MB
  __bf16* Kb  = (__bf16*)(wsb + 256 + 8388608 + 524288 + 4194304);
  __bf16* Vt  = (__bf16*)(wsb + 256 + 8388608 + 524288 + 2 * 4194304);
  _Float16* cp = (_Float16*)(wsb + 256 + 8388608 + 524288 + 3 * 4194304); // 16 MB

  prep_kernel<<<PB + QB + KB + VB, 256, 0, stream>>>(mraw, bmT, Q, K, V, Qb, Kb, Vt);
  attn_l_kernel<<<1024, 256, 0, stream>>>(Qb, Kb, bmT, lp);
  attn_out_kernel<<<1024, 256, 0, stream>>>(Qb, Kb, Vt, bmT, lp, cp, attn);
  ctx_reduce_kernel<<<2048, 256, 0, stream>>>(cp, ctx);
}

// Round 12
// 203.407 us; speedup vs baseline: 1.2328x; 1.2328x over previous
//
#include <hip/hip_runtime.h>

typedef float f32x4 __attribute__((ext_vector_type(4)));
typedef _Float16 f16x4 __attribute__((ext_vector_type(4)));
typedef unsigned int u32x4 __attribute__((ext_vector_type(4)));
typedef __bf16 bf16x8_t __attribute__((ext_vector_type(8)));
typedef __bf16 bf16x4_t __attribute__((ext_vector_type(4)));

#define DEVFN static __device__ __forceinline__

constexpr int BHN = 16;    // B*H
constexpr int SN  = 2048;
constexpr int DN  = 64;
constexpr size_t CTXN = (size_t)BHN * SN * DN;   // 2,097,152
constexpr int NK1 = 4;    // k-split, pass 1
constexpr int NK2 = 4;    // k-split, pass 2

// ---- MFMA asm with internal hazard fencing (verified R2-R7).
DEVFN void qk4_mfma(f32x4& dA, f32x4& dB, bf16x8_t k0v, bf16x8_t k1v,
                    bf16x8_t qA0, bf16x8_t qA1, bf16x8_t qB0, bf16x8_t qB1) {
  asm volatile("s_nop 3\n\t"
               "v_mfma_f32_16x16x32_bf16 %0, %2, %4, %0\n\t"
               "v_mfma_f32_16x16x32_bf16 %1, %2, %6, %1\n\t"
               "v_mfma_f32_16x16x32_bf16 %0, %3, %5, %0\n\t"
               "v_mfma_f32_16x16x32_bf16 %1, %3, %7, %1\n\t"
               "s_nop 7\n\ts_nop 7"
               : "+v"(dA), "+v"(dB)
               : "v"(k0v), "v"(k1v), "v"(qA0), "v"(qA1), "v"(qB0), "v"(qB1));
}

DEVFN void pv8_mfma(f32x4& a0, f32x4& a1, f32x4& a2, f32x4& a3,
                    f32x4& b0, f32x4& b1, f32x4& b2, f32x4& b3,
                    bf16x4_t paA, bf16x4_t paB,
                    bf16x4_t v0, bf16x4_t v1, bf16x4_t v2, bf16x4_t v3) {
  asm volatile("s_nop 3\n\t"
               "v_mfma_f32_16x16x16_bf16 %0, %8, %10, %0\n\t"
               "v_mfma_f32_16x16x16_bf16 %4, %9, %10, %4\n\t"
               "v_mfma_f32_16x16x16_bf16 %1, %8, %11, %1\n\t"
               "v_mfma_f32_16x16x16_bf16 %5, %9, %11, %5\n\t"
               "v_mfma_f32_16x16x16_bf16 %2, %8, %12, %2\n\t"
               "v_mfma_f32_16x16x16_bf16 %6, %9, %12, %6\n\t"
               "v_mfma_f32_16x16x16_bf16 %3, %8, %13, %3\n\t"
               "v_mfma_f32_16x16x16_bf16 %7, %9, %13, %7\n\t"
               "s_nop 7\n\ts_nop 7"
               : "+v"(a0), "+v"(a1), "+v"(a2), "+v"(a3),
                 "+v"(b0), "+v"(b1), "+v"(b2), "+v"(b3)
               : "v"(paA), "v"(paB), "v"(v0), "v"(v1), "v"(v2), "v"(v3));
}

// ---- FUSED prep: blocks [0,2048) pack mask->bmT; [2048,3072) Q->bf16;
// [3072,4096) K->bf16*0.125; [4096,4352) V->tiled Vt.
constexpr int PB = 2048, QB = 1024, KB = 1024, VB = 256;

__global__ __launch_bounds__(256) void prep_kernel(
    const void* __restrict__ mraw, unsigned int* __restrict__ bmT,
    const float* __restrict__ Q, const float* __restrict__ K,
    const float* __restrict__ V, __bf16* __restrict__ Qb,
    __bf16* __restrict__ Kb, __bf16* __restrict__ Vt) {
  const int bid = blockIdx.x;
  const int tidl = threadIdx.x;
  if (bid < PB) {
    // ---- pack mask -> TRANSPOSED bitmask bmT[bh][k/32][q], inline detect.
    __shared__ unsigned int sfl;
    if (tidl == 0) sfl = 0;
    __syncthreads();
    {
      unsigned int f = 0;
      const unsigned int* m32 = (const unsigned int*)mraw;
      for (int i = tidl; i < 4096; i += 256) {
        unsigned int w = m32[i];
        if (w == 0x3F800000u) f |= 2u;
        else if (w > 1u) f |= 1u;
      }
      if (f) atomicOr(&sfl, f);
    }
    __syncthreads();
    const unsigned int fl = (sfl & 2u) ? 2u : ((sfl & 1u) ? 1u : 0u);
    const int tid = bid * 256 + tidl;
    const int NT  = PB * 256;
    if (fl != 1u) {
      const int W = BHN * (SN / 32) * SN;          // 2,097,152
      const unsigned int* m32 = (const unsigned int*)mraw;
      for (int w = tid; w < W; w += NT) {
        const int q   = w & (SN - 1);
        const int kc2 = (w >> 11) & (SN / 32 - 1);
        const int bh  = w >> 17;
        const unsigned int* src = m32 + ((size_t)(bh * SN + q) * SN) + kc2 * 32;
        unsigned int r = 0;
        #pragma unroll
        for (int j = 0; j < 8; ++j) {
          u32x4 v = *(const u32x4*)(src + j * 4);
          r |= ((unsigned)(v[0] != 0u)) << (4 * j)
             | ((unsigned)(v[1] != 0u)) << (4 * j + 1)
             | ((unsigned)(v[2] != 0u)) << (4 * j + 2)
             | ((unsigned)(v[3] != 0u)) << (4 * j + 3);
        }
        bmT[w] = r;
      }
    } else {
      const int W4 = BHN * (SN / 128) * SN;        // 524,288
      const unsigned char* m8 = (const unsigned char*)mraw;
      for (int w4 = tid; w4 < W4; w4 += NT) {
        const int q   = w4 & (SN - 1);
        const int kc8 = (w4 >> 11) & (SN / 128 - 1);
        const int bh  = w4 >> 15;
        const unsigned char* src = m8 + ((size_t)(bh * SN + q) * SN) + kc8 * 128;
        #pragma unroll
        for (int i = 0; i < 4; ++i) {
          const unsigned int* s32 = (const unsigned int*)(src + 32 * i);
          unsigned int r = 0;
          #pragma unroll
          for (int j = 0; j < 8; ++j) {
            unsigned int x = s32[j];
            r |= ((unsigned)((x & 0x000000FFu) != 0u)) << (4 * j)
               | ((unsigned)((x & 0x0000FF00u) != 0u)) << (4 * j + 1)
               | ((unsigned)((x & 0x00FF0000u) != 0u)) << (4 * j + 2)
               | ((unsigned)((x & 0xFF000000u) != 0u)) << (4 * j + 3);
          }
          bmT[((size_t)(bh * (SN / 32) + kc8 * 4 + i)) * SN + q] = r;
        }
      }
    }
  } else if (bid < PB + QB + KB) {
    // ---- f32 -> bf16 convert (Q scale 1, K scale 0.125 exact).
    const bool isK = (bid >= PB + QB);
    const int rb = bid - (isK ? PB + QB : PB);
    const float* src = isK ? K : Q;
    __bf16* dst = isK ? Kb : Qb;
    const float scale = isK ? 0.125f : 1.0f;
    const size_t i = ((size_t)rb * 256 + tidl) * 8;
    f32x4 v0 = *(const f32x4*)(src + i);
    f32x4 v1 = *(const f32x4*)(src + i + 4);
    bf16x8_t o;
    o[0]=(__bf16)(v0[0]*scale); o[1]=(__bf16)(v0[1]*scale);
    o[2]=(__bf16)(v0[2]*scale); o[3]=(__bf16)(v0[3]*scale);
    o[4]=(__bf16)(v1[0]*scale); o[5]=(__bf16)(v1[1]*scale);
    o[6]=(__bf16)(v1[2]*scale); o[7]=(__bf16)(v1[3]*scale);
    *(bf16x8_t*)(dst + i) = o;
  } else {
    // ---- V[k][d] f32 -> TILED Vt: [bh][k/32][d][k%32] bf16 (4 KB tiles).
    const int vb = bid - (PB + QB + KB);
    const int lane = tidl & 63, wv = tidl >> 6;
    const int k0 = ((vb & 15) * 4 + wv) * 32;
    const int bh = vb >> 4;
    const float* src = V + (size_t)bh * SN * DN;
    __bf16* dst = Vt + (((size_t)bh * (SN / 32) + (k0 >> 5)) * DN + lane) * 32;
    bf16x8_t w0, w1, w2, w3;
    #pragma unroll
    for (int i = 0; i < 8; ++i) {
      w0[i] = (__bf16)src[(size_t)(k0 + i) * DN + lane];
      w1[i] = (__bf16)src[(size_t)(k0 + 8 + i) * DN + lane];
      w2[i] = (__bf16)src[(size_t)(k0 + 16 + i) * DN + lane];
      w3[i] = (__bf16)src[(size_t)(k0 + 24 + i) * DN + lane];
    }
    *(bf16x8_t*)(dst)      = w0;
    *(bf16x8_t*)(dst + 8)  = w1;
    *(bf16x8_t*)(dst + 16) = w2;
    *(bf16x8_t*)(dst + 24) = w3;
  }
}

// XCD-pinning decode: all blocks of one bh land on one XCD (bid&7 == bh&7).
DEVFN void swz_decode(int bid, int& bh, int& c, int& x) {
  const int xcd = bid & 7, s8 = bid >> 3;   // s8: 0..127
  bh = xcd + 8 * (s8 >> 6);
  const int r6 = s8 & 63;
  c = r6 >> 4;
  x = r6 & 15;
}

// ---- pass 1: l-partials. LDS-staged K (64-k tiles, double-buffered,
// XOR-swizzled), 2 q-tiles/wave, T14 issue-early/write-late.
__global__ __launch_bounds__(256, 4) void attn_l_kernel(
    const __bf16* __restrict__ Qb, const __bf16* __restrict__ Kb,
    const unsigned int* __restrict__ bmT, float* __restrict__ lpart) {
  __shared__ __align__(16) char Ks[2][8192];
  const int tid = threadIdx.x;
  const int lane = tid & 63, wv = tid >> 6;
  const int qr = lane & 15, g = lane >> 4;
  int bh, c, x;
  swz_decode(blockIdx.x, bh, c, x);
  const int q0 = x * 128 + wv * 32;
  const int CS = SN / NK1, kbase = c * CS;   // 512
  const int NT = CS / 64;                    // 8 tiles

  const __bf16* Qbb = Qb + (size_t)bh * SN * DN;
  const int qA = q0 + qr, qB = q0 + 16 + qr;
  bf16x8_t qfA0 = *(const bf16x8_t*)(Qbb + (size_t)qA * DN + 8 * g);
  bf16x8_t qfA1 = *(const bf16x8_t*)(Qbb + (size_t)qA * DN + 32 + 8 * g);
  bf16x8_t qfB0 = *(const bf16x8_t*)(Qbb + (size_t)qB * DN + 8 * g);
  bf16x8_t qfB1 = *(const bf16x8_t*)(Qbb + (size_t)qB * DN + 32 + 8 * g);
  const size_t rowA = (size_t)bh * SN + qA;
  const size_t rowB = (size_t)bh * SN + qB;
  const unsigned int* bmb = bmT + (size_t)bh * (SN / 32) * SN;
  const int kb2 = kbase >> 5;

  // staging: 8 KB / 256 thr = 32 B/thread (2 x u32x4)
  const int krow = tid >> 2;                 // 0..63
  const int kcol = (tid & 3) * 32;           // 0,32,64,96
  const int swz  = (krow & 7) << 4;
  const int kdst0 = krow * 128 + ((kcol     ) ^ swz);
  const int kdst1 = krow * 128 + ((kcol + 16) ^ swz);
  const char* Ksrc = (const char*)(Kb + (size_t)bh * SN * DN + (size_t)kbase * DN);

  {
    u32x4 a = *(const u32x4*)(Ksrc + krow * 128 + kcol);
    u32x4 b = *(const u32x4*)(Ksrc + krow * 128 + kcol + 16);
    *(u32x4*)&Ks[0][kdst0] = a;
    *(u32x4*)&Ks[0][kdst1] = b;
  }
  __syncthreads();

  float lA = 0.f, lB = 0.f;
  for (int tt = 0; tt < NT; ++tt) {
    const bool pf = (tt + 1 < NT);
    u32x4 a, b;
    if (pf) {
      a = *(const u32x4*)(Ksrc + (tt + 1) * 8192 + krow * 128 + kcol);
      b = *(const u32x4*)(Ksrc + (tt + 1) * 8192 + krow * 128 + kcol + 16);
    }
    const char* Kbuf = Ks[tt & 1];
    const unsigned int wA0 = bmb[(size_t)(kb2 + 2 * tt    ) * SN + qA];
    const unsigned int wA1 = bmb[(size_t)(kb2 + 2 * tt + 1) * SN + qA];
    const unsigned int wB0 = bmb[(size_t)(kb2 + 2 * tt    ) * SN + qB];
    const unsigned int wB1 = bmb[(size_t)(kb2 + 2 * tt + 1) * SN + qB];
    #pragma unroll
    for (int s = 0; s < 4; ++s) {
      const int rk = 16 * s + qr;
      const int rsw = (rk & 7) << 4;
      bf16x8_t kf0 = *(const bf16x8_t*)&Kbuf[rk * 128 + ((16 * g     ) ^ rsw)];
      bf16x8_t kf1 = *(const bf16x8_t*)&Kbuf[rk * 128 + ((64 + 16 * g) ^ rsw)];
      f32x4 aA = {0,0,0,0}, aB = {0,0,0,0};
      qk4_mfma(aA, aB, kf0, kf1, qfA0, qfA1, qfB0, qfB1);
      const unsigned int wmA = (s < 2) ? wA0 : wA1;
      const unsigned int wmB = (s < 2) ? wB0 : wB1;
      const int sh = (s & 1) * 16 + 4 * g;
      lA += ((wmA >> (sh + 0)) & 1u) ? 0.f : __expf(aA[0]);
      lA += ((wmA >> (sh + 1)) & 1u) ? 0.f : __expf(aA[1]);
      lA += ((wmA >> (sh + 2)) & 1u) ? 0.f : __expf(aA[2]);
      lA += ((wmA >> (sh + 3)) & 1u) ? 0.f : __expf(aA[3]);
      lB += ((wmB >> (sh + 0)) & 1u) ? 0.f : __expf(aB[0]);
      lB += ((wmB >> (sh + 1)) & 1u) ? 0.f : __expf(aB[1]);
      lB += ((wmB >> (sh + 2)) & 1u) ? 0.f : __expf(aB[2]);
      lB += ((wmB >> (sh + 3)) & 1u) ? 0.f : __expf(aB[3]);
    }
    if (pf) {
      char* Kn = Ks[(tt + 1) & 1];
      *(u32x4*)&Kn[kdst0] = a;
      *(u32x4*)&Kn[kdst1] = b;
    }
    __syncthreads();
  }
  lA = lA + __shfl_xor(lA, 16); lA = lA + __shfl_xor(lA, 32);
  lB = lB + __shfl_xor(lB, 16); lB = lB + __shfl_xor(lB, 32);
  if (g == 0) {
    lpart[rowA * NK1 + c] = lA;
    lpart[rowB * NK1 + c] = lB;
  }
}

// ---- pass 2: LDS-staged K+V, 2 q-tiles/wave, plain attn stores (R8-proven).
__global__ __launch_bounds__(256, 4) void attn_out_kernel(
    const __bf16* __restrict__ Qb, const __bf16* __restrict__ Kb,
    const __bf16* __restrict__ Vt, const unsigned int* __restrict__ bmT,
    const float* __restrict__ lpart, _Float16* __restrict__ cp,
    float* __restrict__ attn) {
  __shared__ __align__(16) char Ks[2][4096];
  __shared__ __align__(16) char Vs[2][4096];
  const int tid = threadIdx.x;
  const int lane = tid & 63, wv = tid >> 6;
  const int qr = lane & 15, g = lane >> 4;
  int bh, c, x;
  swz_decode(blockIdx.x, bh, c, x);
  const int q0 = x * 128 + wv * 32;
  const int CS = SN / NK2, kbase = c * CS;  // 512
  const int NT = CS / 32;                   // 16 tiles

  const __bf16* Qbb = Qb + (size_t)bh * SN * DN;
  const int qA = q0 + qr, qB = q0 + 16 + qr;
  bf16x8_t qfA0 = *(const bf16x8_t*)(Qbb + (size_t)qA * DN + 8 * g);
  bf16x8_t qfA1 = *(const bf16x8_t*)(Qbb + (size_t)qA * DN + 32 + 8 * g);
  bf16x8_t qfB0 = *(const bf16x8_t*)(Qbb + (size_t)qB * DN + 8 * g);
  bf16x8_t qfB1 = *(const bf16x8_t*)(Qbb + (size_t)qB * DN + 32 + 8 * g);
  const size_t rowA = (size_t)bh * SN + qA;
  const size_t rowB = (size_t)bh * SN + qB;
  f32x4 l4A = *(const f32x4*)(lpart + rowA * NK1);
  f32x4 l4B = *(const f32x4*)(lpart + rowB * NK1);
  const float rlA = 1.0f / (l4A[0] + l4A[1] + l4A[2] + l4A[3]);
  const float rlB = 1.0f / (l4B[0] + l4B[1] + l4B[2] + l4B[3]);
  const unsigned int* bmb = bmT + (size_t)bh * (SN / 32) * SN;
  float* arowA = attn + rowA * SN;
  float* arowB = attn + rowB * SN;

  const int krow = tid >> 3;                 // 0..31
  const int kcolb = (tid & 7) * 16;          // 0..112
  const int kdst = krow * 128 + (kcolb ^ ((krow & 7) << 4));
  const char* Ksrc = (const char*)(Kb + (size_t)bh * SN * DN + (size_t)kbase * DN);
  const int vd = tid >> 2;                   // 0..63
  const int vkb = (tid & 3) * 16;            // 0..48
  const int vdst0 = vd * 64 + ((vkb    ) ^ ((vd & 7) << 3));
  const int vdst1 = vd * 64 + ((vkb + 8) ^ ((vd & 7) << 3));
  const char* Vsrc = (const char*)Vt + ((size_t)bh * (SN / 32) + (kbase >> 5)) * 4096;

  f32x4 cA0 = {0,0,0,0}, cA1 = {0,0,0,0}, cA2 = {0,0,0,0}, cA3 = {0,0,0,0};
  f32x4 cB0 = {0,0,0,0}, cB1 = {0,0,0,0}, cB2 = {0,0,0,0}, cB3 = {0,0,0,0};

  {
    u32x4 kr = *(const u32x4*)(Ksrc + krow * 128 + kcolb);
    u32x4 vr = *(const u32x4*)(Vsrc + tid * 16);
    *(u32x4*)&Ks[0][kdst] = kr;
    *(unsigned long long*)&Vs[0][vdst0] =
        ((unsigned long long)vr[1] << 32) | vr[0];
    *(unsigned long long*)&Vs[0][vdst1] =
        ((unsigned long long)vr[3] << 32) | vr[2];
  }
  __syncthreads();

  for (int tt = 0; tt < NT; ++tt) {
    const bool pf = (tt + 1 < NT);
    u32x4 kr, vr;
    if (pf) {   // T14: issue next-tile loads before compute
      kr = *(const u32x4*)(Ksrc + (tt + 1) * 4096 + krow * 128 + kcolb);
      vr = *(const u32x4*)(Vsrc + (tt + 1) * 4096 + tid * 16);
    }
    const char* Kbuf = Ks[tt & 1];
    const char* Vbuf = Vs[tt & 1];
    const int ktg = kbase + tt * 32;
    const unsigned int wmA = bmb[(size_t)((kbase >> 5) + tt) * SN + qA];
    const unsigned int wmB = bmb[(size_t)((kbase >> 5) + tt) * SN + qB];
    #pragma unroll
    for (int s = 0; s < 2; ++s) {
      const int rk = 16 * s + qr;
      bf16x8_t kf0 = *(const bf16x8_t*)&Kbuf[rk * 128 + ((16 * g     ) ^ ((rk & 7) << 4))];
      bf16x8_t kf1 = *(const bf16x8_t*)&Kbuf[rk * 128 + ((64 + 16 * g) ^ ((rk & 7) << 4))];
      const int vxor = (32 * s + 8 * g) ^ ((qr & 7) << 3);
      bf16x4_t vf0 = *(const bf16x4_t*)&Vbuf[(qr     ) * 64 + vxor];
      bf16x4_t vf1 = *(const bf16x4_t*)&Vbuf[(qr + 16) * 64 + vxor];
      bf16x4_t vf2 = *(const bf16x4_t*)&Vbuf[(qr + 32) * 64 + vxor];
      bf16x4_t vf3 = *(const bf16x4_t*)&Vbuf[(qr + 48) * 64 + vxor];
      f32x4 aA = {0,0,0,0}, aB = {0,0,0,0};
      qk4_mfma(aA, aB, kf0, kf1, qfA0, qfA1, qfB0, qfB1);
      const int sh = 16 * s + 4 * g;
      float pA0 = (((wmA >> (sh + 0)) & 1u) ? 0.f : __expf(aA[0])) * rlA;
      float pA1 = (((wmA >> (sh + 1)) & 1u) ? 0.f : __expf(aA[1])) * rlA;
      float pA2 = (((wmA >> (sh + 2)) & 1u) ? 0.f : __expf(aA[2])) * rlA;
      float pA3 = (((wmA >> (sh + 3)) & 1u) ? 0.f : __expf(aA[3])) * rlA;
      float pB0 = (((wmB >> (sh + 0)) & 1u) ? 0.f : __expf(aB[0])) * rlB;
      float pB1 = (((wmB >> (sh + 1)) & 1u) ? 0.f : __expf(aB[1])) * rlB;
      float pB2 = (((wmB >> (sh + 2)) & 1u) ? 0.f : __expf(aB[2])) * rlB;
      float pB3 = (((wmB >> (sh + 3)) & 1u) ? 0.f : __expf(aB[3])) * rlB;
      *(f32x4*)(arowA + ktg + sh) = (f32x4){pA0, pA1, pA2, pA3};
      *(f32x4*)(arowB + ktg + sh) = (f32x4){pB0, pB1, pB2, pB3};
      bf16x4_t paA = {(__bf16)pA0, (__bf16)pA1, (__bf16)pA2, (__bf16)pA3};
      bf16x4_t paB = {(__bf16)pB0, (__bf16)pB1, (__bf16)pB2, (__bf16)pB3};
      pv8_mfma(cA0, cA1, cA2, cA3, cB0, cB1, cB2, cB3, paA, paB, vf0, vf1, vf2, vf3);
    }
    if (pf) {
      char* Kn = Ks[(tt + 1) & 1];
      char* Vn = Vs[(tt + 1) & 1];
      *(u32x4*)&Kn[kdst] = kr;
      *(unsigned long long*)&Vn[vdst0] = ((unsigned long long)vr[1] << 32) | vr[0];
      *(unsigned long long*)&Vn[vdst1] = ((unsigned long long)vr[3] << 32) | vr[2];
    }
    __syncthreads();
  }
  _Float16* cdst = cp + (size_t)c * CTXN;
  const size_t baseo = (size_t)bh * SN * DN;
  #pragma unroll
  for (int j = 0; j < 4; ++j) {
    const size_t rA = baseo + (size_t)(q0 + 4 * g + j) * DN + qr;
    const size_t rB = baseo + (size_t)(q0 + 16 + 4 * g + j) * DN + qr;
    cdst[rA]      = (_Float16)cA0[j];
    cdst[rA + 16] = (_Float16)cA1[j];
    cdst[rA + 32] = (_Float16)cA2[j];
    cdst[rA + 48] = (_Float16)cA3[j];
    cdst[rB]      = (_Float16)cB0[j];
    cdst[rB + 16] = (_Float16)cB1[j];
    cdst[rB + 32] = (_Float16)cB2[j];
    cdst[rB + 48] = (_Float16)cB3[j];
  }
}

// ---- sum the NK2 f16 partial contexts -> f32 ctx.
__global__ __launch_bounds__(256) void ctx_reduce_kernel(
    const _Float16* __restrict__ cp, float* __restrict__ ctx) {
  const size_t i = ((size_t)blockIdx.x * 256 + threadIdx.x) * 4;
  f16x4 a = *(const f16x4*)(cp + i);
  f16x4 b = *(const f16x4*)(cp + CTXN + i);
  f16x4 d = *(const f16x4*)(cp + 2 * CTXN + i);
  f16x4 e = *(const f16x4*)(cp + 3 * CTXN + i);
  f32x4 s;
  #pragma unroll
  for (int k = 0; k < 4; ++k)
    s[k] = ((float)a[k] + (float)b[k]) + ((float)d[k] + (float)e[k]);
  __builtin_nontemporal_store(s, (f32x4*)(ctx + i));
}

extern "C" void kernel_launch(void* const* d_in, const int* in_sizes, int n_in,
                              void* d_out, int out_size, void* d_ws, size_t ws_size,
                              hipStream_t stream) {
  const float* Q = (const float*)d_in[0];
  const float* K = (const float*)d_in[1];
  const float* V = (const float*)d_in[2];
  const void*  mraw = d_in[3];

  float* out  = (float*)d_out;
  float* ctx  = out;                 // CTXN f32
  float* attn = out + CTXN;          // 67,108,864 f32

  // ws layout (~38.3 MB)
  char* wsb = (char*)d_ws;
  unsigned int* bmT = (unsigned int*)(wsb + 256);                // 8 MB
  float* lp   = (float*)(wsb + 256 + 8388608);                   // 512 KB
  __bf16* Qb  = (__bf16*)(wsb + 256 + 8388608 + 524288);         // 4 MB
  __bf16* Kb  = (__bf16*)(wsb + 256 + 8388608 + 524288 + 4194304);
  __bf16* Vt  = (__bf16*)(wsb + 256 + 8388608 + 524288 + 2 * 4194304);
  _Float16* cp = (_Float16*)(wsb + 256 + 8388608 + 524288 + 3 * 4194304); // 16 MB

  prep_kernel<<<PB + QB + KB + VB, 256, 0, stream>>>(mraw, bmT, Q, K, V, Qb, Kb, Vt);
  attn_l_kernel<<<1024, 256, 0, stream>>>(Qb, Kb, bmT, lp);
  attn_out_kernel<<<1024, 256, 0, stream>>>(Qb, Kb, Vt, bmT, lp, cp, attn);
  ctx_reduce_kernel<<<2048, 256, 0, stream>>>(cp, ctx);
}